// Round 6
// baseline (566.239 us; speedup 1.0000x reference)
//
#include <hip/hip_runtime.h>
#include <hip/hip_bf16.h>
#include <cstdint>
#include <cstddef>

#define SEQ 512
#define BATCH 256
#define IN_DIM 300
#define HID 256

typedef __attribute__((ext_vector_type(8))) short bf16x8;
typedef __attribute__((ext_vector_type(4))) float f32x4;

__device__ __forceinline__ float bitsf(unsigned int u) {
  union { unsigned int u; float f; } v; v.u = u; return v.f;
}
__device__ __forceinline__ unsigned short f2bf(float f) {
  union { float f; unsigned int u; } v; v.f = f;
  unsigned int u = v.u;
  return (unsigned short)((u + 0x7fffu + ((u >> 16) & 1u)) >> 16);  // RNE
}
__device__ __forceinline__ unsigned int pk2(float a, float b) {
  union { __hip_bfloat162 h2; unsigned int u; } p;
  p.h2 = __float22bfloat162_rn(make_float2(a, b));
  return p.u;
}
__device__ __forceinline__ bf16x8 cvt8(float a0,float a1,float a2,float a3,
                                       float a4,float a5,float a6,float a7) {
  union { __hip_bfloat162 h2[4]; bf16x8 v; } c;
  c.h2[0] = __float22bfloat162_rn(make_float2(a0, a1));
  c.h2[1] = __float22bfloat162_rn(make_float2(a2, a3));
  c.h2[2] = __float22bfloat162_rn(make_float2(a4, a5));
  c.h2[3] = __float22bfloat162_rn(make_float2(a6, a7));
  return c.v;
}

// ---------------- kernel 0: W_hh fp32 -> bf16, k-PERMUTED: w_perm[n][P] =
// bf16(W_hh[n][k(P)]), k(P) = (P&192) + 16*(P&3) + ((P>>2)&15).
// This matches the scan's h storage permutation so MFMA k-slots line up.
__global__ __launch_bounds__(256) void conv_whh(const float* __restrict__ W_hh,
                                                unsigned short* __restrict__ w_perm) {
  int idx = blockIdx.x * 256 + threadIdx.x;   // 0..65535
  int n = idx >> 8, P = idx & 255;
  int k = (P & 192) + 16 * (P & 3) + ((P >> 2) & 15);
  w_perm[idx] = f2bf(W_hh[n * 256 + k]);
}

// ---------------- kernel 1: xp2 (scan-permuted, bf16) = 2*(x@W_ih^T + b_ih + b_hh)
// Consumed as uint2 per scan-lane per step:
//   uint2 index = (t*64 + g)*256 + wave*64 + (b&3)*16 + (n&15)
//   .x = cols (n16=0, n16=1) of wave's 64-col span; .y = cols (2, 3).
__global__ __launch_bounds__(256) void gemm_xp(const float* __restrict__ x,
    const float* __restrict__ W_ih, const float* __restrict__ b_ih,
    const float* __restrict__ b_hh, uint2* __restrict__ xpv)
{
  __shared__ unsigned short a_lds[64][40];
  __shared__ unsigned short w_lds[256][40];
  const int tid  = threadIdx.x;
  const int wave = tid >> 6;
  const int lane = tid & 63;
  const int l15  = lane & 15;
  const int quad = lane >> 4;
  const long m0 = (long)blockIdx.x * 64;

  f32x4 acc[4][4];
  #pragma unroll
  for (int mt = 0; mt < 4; ++mt)
    #pragma unroll
    for (int nt = 0; nt < 4; ++nt) acc[mt][nt] = (f32x4){0.f, 0.f, 0.f, 0.f};

  const int ar = tid >> 2;
  const int ac = (tid & 3) * 8;

  float av[8];
  float4 wv[8];
  {
    const float* src = x + (size_t)(m0 + ar) * IN_DIM + ac;
    float2 p0 = *(const float2*)(src + 0);
    float2 p1 = *(const float2*)(src + 2);
    float2 p2 = *(const float2*)(src + 4);
    float2 p3 = *(const float2*)(src + 6);
    av[0]=p0.x; av[1]=p0.y; av[2]=p1.x; av[3]=p1.y;
    av[4]=p2.x; av[5]=p2.y; av[6]=p3.x; av[7]=p3.y;
    #pragma unroll
    for (int i = 0; i < 8; ++i) {
      int e = tid + i * 256;
      wv[i] = *(const float4*)(W_ih + (e >> 3) * IN_DIM + (e & 7) * 4);
    }
  }

  for (int kc = 0; kc < 10; ++kc) {
    *(bf16x8*)&a_lds[ar][ac] = cvt8(av[0],av[1],av[2],av[3],av[4],av[5],av[6],av[7]);
    #pragma unroll
    for (int i = 0; i < 8; ++i) {
      int e = tid + i * 256;
      union { unsigned int u[2]; uint2 d; } pk;
      pk.u[0] = pk2(wv[i].x, wv[i].y);
      pk.u[1] = pk2(wv[i].z, wv[i].w);
      *(uint2*)&w_lds[e >> 3][(e & 7) * 4] = pk.d;
    }
    __syncthreads();
    if (kc < 9) {
      const int k0 = (kc + 1) * 32;
      const float* src = x + (size_t)(m0 + ar) * IN_DIM + (k0 + ac);
      if (k0 + ac + 8 <= IN_DIM) {
        float2 p0 = *(const float2*)(src + 0);
        float2 p1 = *(const float2*)(src + 2);
        float2 p2 = *(const float2*)(src + 4);
        float2 p3 = *(const float2*)(src + 6);
        av[0]=p0.x; av[1]=p0.y; av[2]=p1.x; av[3]=p1.y;
        av[4]=p2.x; av[5]=p2.y; av[6]=p3.x; av[7]=p3.y;
      } else {
        #pragma unroll
        for (int j = 0; j < 8; ++j) av[j] = (k0 + ac + j < IN_DIM) ? src[j] : 0.f;
      }
      #pragma unroll
      for (int i = 0; i < 8; ++i) {
        int e = tid + i * 256;
        int kk = k0 + (e & 7) * 4;
        wv[i] = (kk + 4 <= IN_DIM)
              ? *(const float4*)(W_ih + (e >> 3) * IN_DIM + kk)
              : make_float4(0.f, 0.f, 0.f, 0.f);
      }
    }
    bf16x8 afr[4], bfr[4];
    #pragma unroll
    for (int mt = 0; mt < 4; ++mt)
      afr[mt] = *(const bf16x8*)&a_lds[mt*16 + l15][quad*8];
    #pragma unroll
    for (int nt = 0; nt < 4; ++nt)
      bfr[nt] = *(const bf16x8*)&w_lds[wave*64 + nt*16 + l15][quad*8];
    #pragma unroll
    for (int mt = 0; mt < 4; ++mt)
      #pragma unroll
      for (int nt = 0; nt < 4; ++nt)
        acc[mt][nt] = __builtin_amdgcn_mfma_f32_16x16x32_bf16(afr[mt], bfr[nt], acc[mt][nt], 0, 0, 0);
    __syncthreads();
  }
  // epilogue: one uint2 (4 bf16 cols) per (mt, r)
  const int t = (int)(blockIdx.x >> 2);
  const float kb0 = 2.0f * (b_ih[wave*64 +  0 + l15] + b_hh[wave*64 +  0 + l15]);
  const float kb1 = 2.0f * (b_ih[wave*64 + 16 + l15] + b_hh[wave*64 + 16 + l15]);
  const float kb2 = 2.0f * (b_ih[wave*64 + 32 + l15] + b_hh[wave*64 + 32 + l15]);
  const float kb3 = 2.0f * (b_ih[wave*64 + 48 + l15] + b_hh[wave*64 + 48 + l15]);
  #pragma unroll
  for (int mt = 0; mt < 4; ++mt) {
    const int g = ((int)(blockIdx.x & 3))*16 + mt*4 + quad;
    const size_t base = ((size_t)t*64 + g)*256;
    #pragma unroll
    for (int r = 0; r < 4; ++r) {
      uint2 d;
      d.x = pk2(fmaf(2.0f, acc[mt][0][r], kb0), fmaf(2.0f, acc[mt][1][r], kb1));
      d.y = pk2(fmaf(2.0f, acc[mt][2][r], kb2), fmaf(2.0f, acc[mt][3][r], kb3));
      xpv[base + wave*64 + r*16 + l15] = d;
    }
  }
}

// ---------------- kernel 2: sequential scan. 64 blocks x 256 thr (4 WAVES).
// Block g owns batches [4g, 4g+4). Wave w owns hidden cols [64w, 64w+64)
// (4 n-tiles; W B-frags = 128 VGPRs, 1 wave/SIMD so <=512 VGPR is fine).
// LDS-read-pipe math: A-frags are 8 ds_read_b128 per wave per step
// (irreducible); 4 waves -> 32 instrs (~384 cyc) vs 64 with 8 waves.
// h storage is k-permuted: P = 64w + 4i + nt <-> k = 64w + 16nt + i, matching
// w_perm, so each lane's 4 h outputs are 4 adjacent shorts -> ONE 8B write.
// Lane (quad,l15) owns batch=quad (acc component quad), cols 64w+16nt+l15.
// Stride 272 -> A-read conflicts exactly 2-way (free).
__global__ __launch_bounds__(256, 1) void rnn_scan(
    const unsigned short* __restrict__ w_perm,
    const uint2* __restrict__ xpv, float* __restrict__ hT)
{
  __shared__ alignas(16) unsigned short hbuf[2][4][272];
  const int tid  = threadIdx.x;
  const int wave = tid >> 6;
  const int lane = tid & 63;
  const int l15  = lane & 15;
  const int quad = lane >> 4;
  const int g = blockIdx.x;
  const int c0 = wave * 64;
  const int m = l15 & 3;                      // wrapped A row = batch

  // B fragments from pre-permuted W: element j = W_hh[n][k(kc*32+quad*8+j)]
  bf16x8 wf[4][8];
  #pragma unroll
  for (int nt = 0; nt < 4; ++nt) {
    const int n = c0 + nt*16 + l15;
    #pragma unroll
    for (int kc = 0; kc < 8; ++kc)
      wf[nt][kc] = *(const bf16x8*)(w_perm + (size_t)n*256 + kc*32 + quad*8);
  }

  for (int i = tid; i < 4 * 272; i += 256) (&hbuf[0][0][0])[i] = 0;  // h0 = 0

  const uint2* xb = xpv + (size_t)g * 256 + tid;   // t stride = 64*256 uint2

  __syncthreads();

  uint2 xq[16];
  for (int tc = 0; tc < SEQ / 16; ++tc) {
    #pragma unroll
    for (int j = 0; j < 16; ++j)
      xq[j] = xb[(size_t)(tc * 16 + j) * 16384];
    #pragma unroll
    for (int j = 0; j < 16; ++j) {
      const int cur = j & 1;                  // t parity == j parity
      bf16x8 afr[8];
      #pragma unroll
      for (int kc = 0; kc < 8; ++kc)
        afr[kc] = *(const bf16x8*)&hbuf[cur][m][kc*32 + quad*8];
      f32x4 cA[4], cB[4];
      #pragma unroll
      for (int nt = 0; nt < 4; ++nt) { cA[nt] = (f32x4){0.f,0.f,0.f,0.f}; cB[nt] = cA[nt]; }
      #pragma unroll
      for (int kc = 0; kc < 8; kc += 2) {
        #pragma unroll
        for (int nt = 0; nt < 4; ++nt) {
          cA[nt] = __builtin_amdgcn_mfma_f32_16x16x32_bf16(afr[kc],   wf[nt][kc],   cA[nt], 0, 0, 0);
          cB[nt] = __builtin_amdgcn_mfma_f32_16x16x32_bf16(afr[kc+1], wf[nt][kc+1], cB[nt], 0, 0, 0);
        }
      }
      float xv[4], h[4];
      xv[0] = bitsf(xq[j].x << 16);
      xv[1] = bitsf(xq[j].x & 0xffff0000u);
      xv[2] = bitsf(xq[j].y << 16);
      xv[3] = bitsf(xq[j].y & 0xffff0000u);
      #pragma unroll
      for (int nt = 0; nt < 4; ++nt) {
        f32x4 s = cA[nt] + cB[nt];
        // component 'quad' = this lane's batch (D rows repeat batches 0..3)
        float a = (quad & 2) ? ((quad & 1) ? s[3] : s[2])
                             : ((quad & 1) ? s[1] : s[0]);
        float y = fmaf(2.0f, a, xv[nt]);      // 2*(h@W^T + x + b)
        h[nt] = fmaf(-2.0f, __builtin_amdgcn_rcpf(__expf(y) + 1.0f), 1.0f);
      }
      if (j < 15 || tc < SEQ/16 - 1) {
        uint2 w2;
        w2.x = pk2(h[0], h[1]);
        w2.y = pk2(h[2], h[3]);
        *(uint2*)&hbuf[1 - cur][quad][wave*64 + l15*4] = w2;   // P=64w+4*l15+nt
      } else {
        #pragma unroll
        for (int nt = 0; nt < 4; ++nt)
          hT[(size_t)(g*4 + quad) * HID + c0 + nt*16 + l15] = h[nt];
      }
      __syncthreads();
    }
  }
}

// ---------------- kernel 3: logits + log_softmax. 1 wave/batch.
__global__ __launch_bounds__(64) void fc_head(const float* __restrict__ hT,
    const float* __restrict__ W_fc, const float* __restrict__ b_fc,
    float* __restrict__ out)
{
  const int b = blockIdx.x;
  const int l = threadIdx.x;
  float s0 = 0.f, s1 = 0.f;
  #pragma unroll
  for (int j0 = 0; j0 < HID; j0 += 64) {
    float h = hT[(size_t)b * HID + j0 + l];
    s0 += h * W_fc[j0 + l];
    s1 += h * W_fc[HID + j0 + l];
  }
  #pragma unroll
  for (int off = 32; off > 0; off >>= 1) {
    s0 += __shfl_xor(s0, off, 64);
    s1 += __shfl_xor(s1, off, 64);
  }
  if (l == 0) {
    float l0 = s0 + b_fc[0], l1 = s1 + b_fc[1];
    float m = fmaxf(l0, l1);
    float lse = m + logf(expf(l0 - m) + expf(l1 - m));
    out[b*2 + 0] = l0 - lse;
    out[b*2 + 1] = l1 - lse;
  }
}

extern "C" void kernel_launch(void* const* d_in, const int* in_sizes, int n_in,
                              void* d_out, int out_size, void* d_ws, size_t ws_size,
                              hipStream_t stream) {
  const float* x    = (const float*)d_in[0];
  const float* W_ih = (const float*)d_in[1];
  const float* W_hh = (const float*)d_in[2];
  const float* b_ih = (const float*)d_in[3];
  const float* b_hh = (const float*)d_in[4];
  const float* W_fc = (const float*)d_in[5];
  const float* b_fc = (const float*)d_in[6];
  float* out = (float*)d_out;

  const size_t xp_bytes = (size_t)SEQ * BATCH * HID * 2;   // 67,108,864
  const size_t wp_bytes = (size_t)256 * 256 * 2;           // 131,072
  const size_t ht_bytes = (size_t)BATCH * HID * 4;         // 262,144
  if (ws_size < xp_bytes + wp_bytes + ht_bytes) return;

  char* ws = (char*)d_ws;
  uint2*          xpv    = (uint2*)ws;
  unsigned short* w_perm = (unsigned short*)(ws + xp_bytes);
  float*          hT     = (float*)(ws + xp_bytes + wp_bytes);

  hipLaunchKernelGGL(conv_whh, dim3(256),  dim3(256), 0, stream, W_hh, w_perm);
  hipLaunchKernelGGL(gemm_xp,  dim3(2048), dim3(256), 0, stream, x, W_ih, b_ih, b_hh, xpv);
  hipLaunchKernelGGL(rnn_scan, dim3(64),   dim3(256), 0, stream, w_perm, xpv, hT);
  hipLaunchKernelGGL(fc_head,  dim3(BATCH), dim3(64), 0, stream, hT, W_fc, b_fc, out);
}